// Round 1
// baseline (19545.946 us; speedup 1.0000x reference)
//
#include <hip/hip_runtime.h>
#include <cmath>

#define TT 512
#define BB 64
#define HH 512
#define II 128

// ---------------------------------------------------------------------------
// Transpose x: [64][512][128] (b,t,k) -> xT: [512][128][64] (t,k,b)
// so that recurrence-time reads are coalesced with lanes = batch.
// ---------------------------------------------------------------------------
__global__ __launch_bounds__(1024) void k_transpose_x(const float* __restrict__ x,
                                                      float* __restrict__ xT) {
  __shared__ float tile[64][65];  // [k][b], padded: conflict-free both phases
  const int t  = blockIdx.x >> 1;
  const int k0 = (blockIdx.x & 1) << 6;
  const int lk = threadIdx.x & 63;   // lane dim = k  (coalesced global read)
  const int lb = threadIdx.x >> 6;   // 16 b per pass
#pragma unroll
  for (int bp = 0; bp < 64; bp += 16) {
    const int b = bp + lb;
    tile[lk][b] = x[((size_t)b * TT + t) * II + k0 + lk];
  }
  __syncthreads();
  const int b2  = threadIdx.x & 63;  // lane dim = b  (coalesced global write)
  const int kk0 = threadIdx.x >> 6;
#pragma unroll
  for (int kp = 0; kp < 64; kp += 16) {
    const int kk = kp + kk0;
    xT[((size_t)t * II + k0 + kk) * BB + b2] = tile[kk][b2];
  }
}

__device__ __forceinline__ float sigm(float v) { return 1.0f / (1.0f + expf(-v)); }

// ---------------------------------------------------------------------------
// One pipelined step: blocks 0..127 = layer0 @ t=s, blocks 128..255 = layer1 @ t=s-1.
// Block covers 4 hidden units x 4 gates x 64 batches.
// Thread (kseg in 8, rowgroup in 2, b in 64) computes 8 partial dots (R=8 rows),
// reduced via LDS. h layout is [k][b] so lanes (=b) are coalesced; weight reads
// are wave-uniform broadcasts.
// ---------------------------------------------------------------------------
__global__ __launch_bounds__(1024, 1) void k_lstm_step(
    const float* __restrict__ xT,
    const float* __restrict__ W_ih0, const float* __restrict__ W_hh0,
    const float* __restrict__ b_ih0, const float* __restrict__ b_hh0,
    const float* __restrict__ W_ih1, const float* __restrict__ W_hh1,
    const float* __restrict__ b_ih1, const float* __restrict__ b_hh1,
    float* __restrict__ h0ring, float* __restrict__ h1ring,
    float* __restrict__ c0, float* __restrict__ c1, const int s)
{
  const int L  = blockIdx.x >> 7;          // 0 or 1
  const int ub = (blockIdx.x & 127) << 2;  // unit base (4 units per block)
  const int t  = (L == 0) ? s : s - 1;
  if (t < 0 || t >= TT) return;            // uniform per block
  const bool first = (t == 0);

  const int tid  = threadIdx.x;
  const int kseg = tid >> 7;        // 0..7
  const int rg   = (tid >> 6) & 1;  // 0..1
  const int b    = tid & 63;

  // input sources: A = feedforward input, B = recurrent h
  const float* srcA; const float* WA; int KA;
  const float* srcB; const float* WB;
  if (L == 0) {
    srcA = xT + (size_t)t * (II * BB);          WA = W_ih0; KA = II;
    srcB = h0ring + ((s - 1) & 1) * (HH * BB);  WB = W_hh0;      // h0[t-1]
  } else {
    srcA = h0ring + ((s - 1) & 1) * (HH * BB);  WA = W_ih1; KA = HH;  // h0[t]
    srcB = h1ring + (s & 1) * (HH * BB);        WB = W_hh1;      // h1[t-1]
  }

  // 8 rows per thread: local row lr = rg*8 + r; u = lr>>2, q(gate) = lr&3
  int rowA[8], rowB[8];
#pragma unroll
  for (int r = 0; r < 8; ++r) {
    const int lr = (rg << 3) + r;
    const int u = lr >> 2, q = lr & 3;
    const int G = q * HH + ub + u;   // global gate-row (i,f,g,o chunk order)
    rowA[r] = G * KA;
    rowB[r] = G * HH;
  }

  float acc[8];
#pragma unroll
  for (int r = 0; r < 8; ++r) acc[r] = 0.0f;

  { // A part (always present)
    const int kn  = KA >> 3;         // 16 (L0) or 64 (L1) k's per kseg
    const int ka0 = kseg * kn;
    for (int kk = 0; kk < kn; kk += 4) {
      const int k = ka0 + kk;
      const float v0 = srcA[(k + 0) * BB + b];
      const float v1 = srcA[(k + 1) * BB + b];
      const float v2 = srcA[(k + 2) * BB + b];
      const float v3 = srcA[(k + 3) * BB + b];
#pragma unroll
      for (int r = 0; r < 8; ++r) {
        const float4 w = *(const float4*)(WA + rowA[r] + k);
        acc[r] = fmaf(w.x, v0, fmaf(w.y, v1, fmaf(w.z, v2, fmaf(w.w, v3, acc[r]))));
      }
    }
  }
  if (!first) { // B part (recurrent h; h_prev == 0 at t==0)
    const int kn  = HH >> 3;  // 64
    const int kb0 = kseg * kn;
    for (int kk = 0; kk < kn; kk += 4) {
      const int k = kb0 + kk;
      const float v0 = srcB[(k + 0) * BB + b];
      const float v1 = srcB[(k + 1) * BB + b];
      const float v2 = srcB[(k + 2) * BB + b];
      const float v3 = srcB[(k + 3) * BB + b];
#pragma unroll
      for (int r = 0; r < 8; ++r) {
        const float4 w = *(const float4*)(WB + rowB[r] + k);
        acc[r] = fmaf(w.x, v0, fmaf(w.y, v1, fmaf(w.z, v2, fmaf(w.w, v3, acc[r]))));
      }
    }
  }

  // reduce 8 ksegs -> gate values; lanes = b everywhere -> 2-way (free) banks
  __shared__ float part[16][8][64];   // [row][kseg][b]  32 KB
  __shared__ float gates[16][64];     //  4 KB
#pragma unroll
  for (int r = 0; r < 8; ++r) part[(rg << 3) + r][kseg][b] = acc[r];
  __syncthreads();

  {
    const int row = tid >> 6;  // 0..15
    const int bb  = tid & 63;
    float g = 0.0f;
#pragma unroll
    for (int ks = 0; ks < 8; ++ks) g += part[row][ks][bb];
    const int u = row >> 2, q = row & 3;
    const int G = q * HH + ub + u;
    const float bias = (L == 0) ? (b_ih0[G] + b_hh0[G]) : (b_ih1[G] + b_hh1[G]);
    gates[row][bb] = g + bias;
  }
  __syncthreads();

  if (tid < 256) {  // one thread per (unit, batch): the cell update
    const int u = tid >> 6, bb = tid & 63;
    const float gi = sigm(gates[(u << 2) + 0][bb]);
    const float gf = sigm(gates[(u << 2) + 1][bb]);
    const float gg = tanhf(gates[(u << 2) + 2][bb]);
    const float go = sigm(gates[(u << 2) + 3][bb]);
    const int j = ub + u;
    float* cbuf = (L == 0) ? c0 : c1;
    const float cold = first ? 0.0f : cbuf[j * BB + bb];
    const float cn = gf * cold + gi * gg;
    const float hn = go * tanhf(cn);
    cbuf[j * BB + bb] = cn;
    float* hdst = ((L == 0) ? h0ring : h1ring) + (t & 1) * (HH * BB);
    hdst[j * BB + bb] = hn;   // h stored [j][b]
  }
}

// ---------------------------------------------------------------------------
// out[b] = sum_j h1_last[j][b] * Wl[j] + bl[0]
// ---------------------------------------------------------------------------
__global__ __launch_bounds__(512) void k_final(const float* __restrict__ h1last,
                                               const float* __restrict__ Wl,
                                               const float* __restrict__ bl,
                                               float* __restrict__ out) {
  __shared__ float red[8][64];
  const int jg = threadIdx.x >> 6, b = threadIdx.x & 63;
  float a = 0.0f;
  for (int jj = 0; jj < 64; ++jj) {
    const int j = (jg << 6) + jj;
    a += h1last[j * BB + b] * Wl[j];
  }
  red[jg][b] = a;
  __syncthreads();
  if (threadIdx.x < 64) {
    float s = bl[0];
#pragma unroll
    for (int g = 0; g < 8; ++g) s += red[g][threadIdx.x];
    out[threadIdx.x] = s;
  }
}

extern "C" void kernel_launch(void* const* d_in, const int* in_sizes, int n_in,
                              void* d_out, int out_size, void* d_ws, size_t ws_size,
                              hipStream_t stream) {
  const float* x     = (const float*)d_in[0];
  const float* W_ih0 = (const float*)d_in[1];
  const float* W_hh0 = (const float*)d_in[2];
  const float* b_ih0 = (const float*)d_in[3];
  const float* b_hh0 = (const float*)d_in[4];
  const float* W_ih1 = (const float*)d_in[5];
  const float* W_hh1 = (const float*)d_in[6];
  const float* b_ih1 = (const float*)d_in[7];
  const float* b_hh1 = (const float*)d_in[8];
  const float* Wl    = (const float*)d_in[9];
  const float* bl    = (const float*)d_in[10];
  float* out = (float*)d_out;

  // workspace layout (floats). Total ~17.6 MB.
  float* ws     = (float*)d_ws;
  float* xT     = ws;                      // 512*128*64 = 4194304
  float* h0ring = xT + (size_t)TT * II * BB;  // 2*512*64  = 65536
  float* h1ring = h0ring + 2 * HH * BB;       // 2*512*64  = 65536
  float* c0     = h1ring + 2 * HH * BB;       // 512*64    = 32768
  float* c1     = c0 + HH * BB;               // 512*64    = 32768
  // No memset needed: every location is written before it is read each call
  // (t==0 steps skip h_prev/c_old reads entirely).

  k_transpose_x<<<1024, 1024, 0, stream>>>(x, xT);

  // Pipelined recurrence: 513 sequential phases (layer0 @ t=s, layer1 @ t=s-1)
  for (int s = 0; s <= TT; ++s) {
    k_lstm_step<<<256, 1024, 0, stream>>>(xT, W_ih0, W_hh0, b_ih0, b_hh0,
                                          W_ih1, W_hh1, b_ih1, b_hh1,
                                          h0ring, h1ring, c0, c1, s);
  }

  // h1[T-1] lives at ring parity (T-1)&1 == 1
  k_final<<<1, 512, 0, stream>>>(h1ring + HH * BB, Wl, bl, out);
}